// Round 7
// baseline (624.287 us; speedup 1.0000x reference)
//
#include <hip/hip_runtime.h>
#include <hip/hip_bf16.h>
#include <math.h>

#define Nn 20480
#define Cc 128
#define Hh 8
#define Ll 4
#define NWw 320
#define BN 81920   // B*N

typedef short sv8 __attribute__((ext_vector_type(8)));
typedef __bf16 bfv8 __attribute__((ext_vector_type(8)));
typedef float f32x4 __attribute__((ext_vector_type(4)));

__device__ __forceinline__ f32x4 mfma16(sv8 a, sv8 b, f32x4 c) {
    return __builtin_amdgcn_mfma_f32_16x16x32_bf16(
        __builtin_bit_cast(bfv8, a), __builtin_bit_cast(bfv8, b), c, 0, 0, 0);
}
__device__ __forceinline__ ushort f2bf(float f) {
    uint u = __float_as_uint(f);
    u += 0x7fffu + ((u >> 16) & 1u);
    return (ushort)(u >> 16);
}
// packed f32 pair -> 2 bf16 in one VALU op (RNE, matches f2bf)
__device__ __forceinline__ uint pk2bf(float lo, float hi) {
    uint r;
    asm("v_cvt_pk_bf16_f32 %0, %1, %2" : "=v"(r) : "v"(lo), "v"(hi));
    return r;
}
__device__ __forceinline__ float fast_gelu(float x) {
    float z = 0.7978845608f * (x + 0.044715f * x * x * x);
    return x * __builtin_amdgcn_rcpf(1.0f + __expf(-2.0f * z));
}

// ---------- stable counting sort of window_ids ----------
__global__ __launch_bounds__(64) void rank_kernel(const int* __restrict__ wid,
        int* __restrict__ lrank, int* __restrict__ hist) {
    __shared__ int keys[64];
    int c = blockIdx.x, lane = threadIdx.x;
    for (int j = lane; j < NWw; j += 64) hist[c * NWw + j] = 0;
    int i = c * 64 + lane;
    int w = wid[i];
    keys[lane] = w;
    __syncthreads();
    int rank = 0, total = 0;
    for (int j = 0; j < 64; ++j) {
        int kj = keys[j];
        total += (kj == w);
        rank += (j < lane && kj == w) ? 1 : 0;
    }
    lrank[i] = rank;
    if (rank == 0) hist[c * NWw + w] = total;
}
__global__ __launch_bounds__(64) void prefix_kernel(int* __restrict__ hist) {
    int w = blockIdx.x, lane = threadIdx.x;
    int running = 0;
    for (int it = 0; it < NWw / 64; ++it) {
        int c = it * 64 + lane;
        int v = hist[c * NWw + w];
        int orig = v;
        #pragma unroll
        for (int d = 1; d < 64; d <<= 1) {
            int tt = __shfl_up(v, d, 64);
            if (lane >= d) v += tt;
        }
        hist[c * NWw + w] = running + v - orig;
        running += __shfl(v, 63, 64);
    }
}
__global__ __launch_bounds__(64) void scatter_kernel(const int* __restrict__ wid,
        const int* __restrict__ lrank, const int* __restrict__ hist,
        int* __restrict__ sidx) {
    int c = blockIdx.x, lane = threadIdx.x;
    int i = c * 64 + lane;
    int w = wid[i];
    sidx[w * 64 + hist[c * NWw + w] + lrank[i]] = i;
}

// ---------- weight convert + transpose to bf16 [N][K] ----------
__global__ __launch_bounds__(256) void wconv_kernel(
    const float* __restrict__ Wqkv, const float* __restrict__ Wproj,
    const float* __restrict__ W1, const float* __restrict__ W2,
    ushort* __restrict__ wt) {
    int id = blockIdx.x * 256 + threadIdx.x;      // < 786432
    int l = id / 196608;
    int r = id % 196608;
    const float* src; int dst;
    if (r < 49152) { int n = r % 384, k = r / 384;
        src = Wqkv + l * 49152 + k * 384 + n; dst = l * 196608 + n * 128 + k; }
    else if (r < 65536) { int rr = r - 49152; int n = rr % 128, k = rr / 128;
        src = Wproj + l * 16384 + k * 128 + n; dst = l * 196608 + 49152 + n * 128 + k; }
    else if (r < 131072) { int rr = r - 65536; int n = rr % 512, k = rr / 512;
        src = W1 + l * 65536 + k * 512 + n; dst = l * 196608 + 65536 + n * 128 + k; }
    else { int rr = r - 131072; int n = rr % 128, k = rr / 128;
        src = W2 + l * 65536 + k * 128 + n; dst = l * 196608 + 131072 + n * 512 + k; }
    wt[dst] = f2bf(*src);
}

// ---------- fused attention block (unchanged) ----------
__global__ __launch_bounds__(256, 2) void attn_fused_kernel(
    const float* __restrict__ xsrc, float* __restrict__ xdst,
    const ushort* __restrict__ wqkvT, const float* __restrict__ bqkv,
    const float* __restrict__ relb, const ushort* __restrict__ wprojT,
    const float* __restrict__ bproj, const float* __restrict__ g1,
    const float* __restrict__ be1, const int* __restrict__ sidx) {
    __shared__ __align__(16) ushort hl_[64][128];
    __shared__ __align__(16) ushort qkn[64][256];
    __shared__ __align__(16) ushort vT[128][76];
    __shared__ __align__(16) ushort pt[4][16][76];
    __shared__ int ridx[64];

    int t = threadIdx.x;
    int wave = t >> 6, lane = t & 63;
    int lr = lane & 15, lg = lane >> 4;
    int wb = blockIdx.x;
    int bN = (wb / NWw) * Nn;
    int p0 = (wb % NWw) * 64;

    if (t < 64) ridx[t] = sidx[p0 + t];
    __syncthreads();

    // ---- phase 1: gather + LN1 -> hl_ (bf16, swizzled)
    {
        int hl2 = lane & 31, hb = lane >> 5;
        float4 gg = *(const float4*)(g1 + hl2 * 4);
        float4 bb = *(const float4*)(be1 + hl2 * 4);
        #pragma unroll
        for (int it = 0; it < 8; ++it) {
            int row = it * 8 + wave * 2 + hb;
            int gi = bN + ridx[row];
            float4 v = *(const float4*)(xsrc + (size_t)gi * Cc + hl2 * 4);
            float s = v.x + v.y + v.z + v.w;
            s += __shfl_xor(s, 1, 64);  s += __shfl_xor(s, 2, 64);
            s += __shfl_xor(s, 4, 64);  s += __shfl_xor(s, 8, 64);
            s += __shfl_xor(s, 16, 64);
            float mu = s * 0.0078125f;
            float d0 = v.x - mu, d1 = v.y - mu, d2 = v.z - mu, d3 = v.w - mu;
            float q = d0 * d0 + d1 * d1 + d2 * d2 + d3 * d3;
            q += __shfl_xor(q, 1, 64);  q += __shfl_xor(q, 2, 64);
            q += __shfl_xor(q, 4, 64);  q += __shfl_xor(q, 8, 64);
            q += __shfl_xor(q, 16, 64);
            float rs = rsqrtf(q * 0.0078125f + 1e-5f);
            uint2 pk;
            pk.x = pk2bf(d0 * rs * gg.x + bb.x, d1 * rs * gg.y + bb.y);
            pk.y = pk2bf(d2 * rs * gg.z + bb.z, d3 * rs * gg.w + bb.w);
            *(uint2*)&hl_[row][(hl2 * 4) ^ ((row & 7) << 3)] = pk;
        }
    }
    __syncthreads();

    // ---- phase 2: QKV GEMM; wave computes its own 2 heads' q,k,v (96 cols)
    {
        f32x4 acc[4][6] = {};
        #pragma unroll
        for (int ks = 0; ks < 4; ++ks) {
            int k0 = ks * 32 + lg * 8;
            sv8 a[4], b[6];
            #pragma unroll
            for (int rf = 0; rf < 4; ++rf) {
                int row = rf * 16 + lr;
                a[rf] = *(const sv8*)&hl_[row][k0 ^ ((row & 7) << 3)];
            }
            #pragma unroll
            for (int nf = 0; nf < 6; ++nf) {
                int gcol = (nf < 2 ? 32 * wave + nf * 16
                          : nf < 4 ? 128 + 32 * wave + (nf - 2) * 16
                                   : 256 + 32 * wave + (nf - 4) * 16) + lr;
                b[nf] = *(const sv8*)(wqkvT + (size_t)gcol * 128 + k0);
            }
            #pragma unroll
            for (int rf = 0; rf < 4; ++rf)
                #pragma unroll
                for (int nf = 0; nf < 6; ++nf)
                    acc[rf][nf] = mfma16(a[rf], b[nf], acc[rf][nf]);
        }
        #pragma unroll
        for (int nf = 0; nf < 6; ++nf) {
            int gcol = (nf < 2 ? 32 * wave + nf * 16
                      : nf < 4 ? 128 + 32 * wave + (nf - 2) * 16
                               : 256 + 32 * wave + (nf - 4) * 16) + lr;
            float bs = bqkv[gcol];
            if (nf < 4) {
                #pragma unroll
                for (int rf = 0; rf < 4; ++rf)
                    #pragma unroll
                    for (int r = 0; r < 4; ++r) {
                        int row = rf * 16 + lg * 4 + r;
                        qkn[row][gcol ^ ((row & 7) << 3)] = f2bf(acc[rf][nf][r] + bs);
                    }
            } else {
                int dcol = gcol - 256;
                #pragma unroll
                for (int rf = 0; rf < 4; ++rf) {
                    uint2 pk;
                    pk.x = pk2bf(acc[rf][nf][0] + bs, acc[rf][nf][1] + bs);
                    pk.y = pk2bf(acc[rf][nf][2] + bs, acc[rf][nf][3] + bs);
                    *(uint2*)&vT[dcol][rf * 16 + lg * 4] = pk;
                }
            }
        }
    }
    __syncthreads();

    // ---- phase 3: attention via swapped QK^T (S^T = K Q^T), 2 heads per wave
    f32x4 zz = {0.f, 0.f, 0.f, 0.f};
    #pragma unroll
    for (int hi = 0; hi < 2; ++hi) {
        int hh = wave * 2 + hi;
        float rb = relb[hh];
        sv8 bv[2];
        #pragma unroll
        for (int ks = 0; ks < 2; ++ks)
            bv[ks] = *(const sv8*)&vT[hh * 16 + lr][ks * 32 + lg * 8];
        sv8 aq[4], bk[4];
        sv8 z = {0, 0, 0, 0, 0, 0, 0, 0};
        bool lo = (lg < 2);
        #pragma unroll
        for (int f = 0; f < 4; ++f) {
            aq[f] = z; bk[f] = z;
            if (lo) {
                int row = f * 16 + lr;
                aq[f] = *(const sv8*)&qkn[row][(hh * 16 + lg * 8) ^ ((row & 7) << 3)];
                bk[f] = *(const sv8*)&qkn[row][(128 + hh * 16 + lg * 8) ^ ((row & 7) << 3)];
            }
        }
        f32x4 s[4][4];
        #pragma unroll
        for (int kt = 0; kt < 4; ++kt)
            #pragma unroll
            for (int qt = 0; qt < 4; ++qt)
                s[kt][qt] = mfma16(bk[kt], aq[qt], zz);

        f32x4 o[4];
        #pragma unroll
        for (int qt = 0; qt < 4; ++qt) {
            float v[16];
            #pragma unroll
            for (int kt = 0; kt < 4; ++kt)
                #pragma unroll
                for (int r = 0; r < 4; ++r)
                    v[kt * 4 + r] = s[kt][qt][r] * 0.25f + rb;
            float m0 = fmaxf(fmaxf(fmaxf(v[0], v[1]), fmaxf(v[2], v[3])),
                             fmaxf(fmaxf(v[4], v[5]), fmaxf(v[6], v[7])));
            float m1 = fmaxf(fmaxf(fmaxf(v[8], v[9]), fmaxf(v[10], v[11])),
                             fmaxf(fmaxf(v[12], v[13]), fmaxf(v[14], v[15])));
            float mx = fmaxf(m0, m1);
            mx = fmaxf(mx, __shfl_xor(mx, 16, 64));
            mx = fmaxf(mx, __shfl_xor(mx, 32, 64));
            float sum = 0.f;
            #pragma unroll
            for (int i = 0; i < 16; ++i) {
                v[i] = __expf(v[i] - mx);
                sum += v[i];
            }
            sum += __shfl_xor(sum, 16, 64);
            sum += __shfl_xor(sum, 32, 64);
            float inv = __builtin_amdgcn_rcpf(sum);
            #pragma unroll
            for (int kt = 0; kt < 4; ++kt) {
                uint2 pk;
                pk.x = pk2bf(v[kt * 4 + 0] * inv, v[kt * 4 + 1] * inv);
                pk.y = pk2bf(v[kt * 4 + 2] * inv, v[kt * 4 + 3] * inv);
                *(uint2*)&pt[wave][lr][kt * 16 + lg * 4] = pk;
            }
            sv8 ap0 = *(const sv8*)&pt[wave][lr][lg * 8];
            sv8 ap1 = *(const sv8*)&pt[wave][lr][32 + lg * 8];
            o[qt] = mfma16(ap0, bv[0], zz);
            o[qt] = mfma16(ap1, bv[1], o[qt]);
        }
        #pragma unroll
        for (int qt = 0; qt < 4; ++qt)
            #pragma unroll
            for (int r = 0; r < 4; ++r) {
                int row = qt * 16 + lg * 4 + r;
                hl_[row][(hh * 16 + lr) ^ ((row & 7) << 3)] = f2bf(o[qt][r]);
            }
    }
    __syncthreads();

    // ---- phase 4: proj + bias + residual, scatter to original rows
    {
        f32x4 acc[4][2] = {};
        #pragma unroll
        for (int ks = 0; ks < 4; ++ks) {
            int k0 = ks * 32 + lg * 8;
            sv8 a[4], b[2];
            #pragma unroll
            for (int rf = 0; rf < 4; ++rf) {
                int row = rf * 16 + lr;
                a[rf] = *(const sv8*)&hl_[row][k0 ^ ((row & 7) << 3)];
            }
            #pragma unroll
            for (int nf = 0; nf < 2; ++nf)
                b[nf] = *(const sv8*)(wprojT + (size_t)(wave * 32 + nf * 16 + lr) * 128 + k0);
            #pragma unroll
            for (int rf = 0; rf < 4; ++rf)
                #pragma unroll
                for (int nf = 0; nf < 2; ++nf)
                    acc[rf][nf] = mfma16(a[rf], b[nf], acc[rf][nf]);
        }
        #pragma unroll
        for (int nf = 0; nf < 2; ++nf) {
            int col = wave * 32 + nf * 16 + lr;
            float bs = bproj[col];
            #pragma unroll
            for (int rf = 0; rf < 4; ++rf)
                #pragma unroll
                for (int r = 0; r < 4; ++r) {
                    int row = rf * 16 + lg * 4 + r;
                    int gi = bN + ridx[row];
                    size_t ad = (size_t)gi * Cc + col;
                    xdst[ad] = xsrc[ad] + acc[rf][nf][r] + bs;
                }
        }
    }
}

// ---------- MLP: barrier-free wave-solo. 4 waves/block, each wave owns 32 tokens ----------
// LN2 in registers -> 16 chunks of 32 hidden: swapped MLP1 -> gelu -> wave-private LDS
// transpose (dbuf, stride-40 pad) -> MLP2 partial accumulate. ZERO __syncthreads.
__global__ __launch_bounds__(256, 2) void mlp_fused_kernel(
    const float* __restrict__ xsrc, float* __restrict__ xdst,
    const ushort* __restrict__ w1T, const float* __restrict__ b1,
    const ushort* __restrict__ w2T, const float* __restrict__ b2,
    const float* __restrict__ g2, const float* __restrict__ be2) {
    __shared__ __align__(16) ushort sc[4][2][32][40];   // 20.5 KB, wave-private slabs
    int t = threadIdx.x, wave = t >> 6, lane = t & 63;
    int lr = lane & 15, lg = lane >> 4;
    int t0 = blockIdx.x * 128 + wave * 32;

    // ---- LN2 fully in registers -> h B-fragments hfr[tf][kc]
    // lane holds x[t0 + tf*16 + lr][kc*32 + lg*8 + j], j=0..7
    sv8 hfr[2][4];
    {
        float xv[2][4][8];
        float sum[2] = {0.f, 0.f};
        #pragma unroll
        for (int tf = 0; tf < 2; ++tf) {
            const float* xr = xsrc + (size_t)(t0 + tf * 16 + lr) * Cc + lg * 8;
            #pragma unroll
            for (int kc = 0; kc < 4; ++kc) {
                float4 a = *(const float4*)(xr + kc * 32);
                float4 b = *(const float4*)(xr + kc * 32 + 4);
                xv[tf][kc][0] = a.x; xv[tf][kc][1] = a.y; xv[tf][kc][2] = a.z; xv[tf][kc][3] = a.w;
                xv[tf][kc][4] = b.x; xv[tf][kc][5] = b.y; xv[tf][kc][6] = b.z; xv[tf][kc][7] = b.w;
                sum[tf] += a.x + a.y + a.z + a.w + b.x + b.y + b.z + b.w;
            }
            sum[tf] += __shfl_xor(sum[tf], 16, 64);
            sum[tf] += __shfl_xor(sum[tf], 32, 64);
        }
        #pragma unroll
        for (int tf = 0; tf < 2; ++tf) {
            float mu = sum[tf] * 0.0078125f;
            float q = 0.f;
            #pragma unroll
            for (int kc = 0; kc < 4; ++kc)
                #pragma unroll
                for (int j = 0; j < 8; ++j) {
                    float d = xv[tf][kc][j] - mu;
                    xv[tf][kc][j] = d;
                    q += d * d;
                }
            q += __shfl_xor(q, 16, 64);
            q += __shfl_xor(q, 32, 64);
            float rs = rsqrtf(q * 0.0078125f + 1e-5f);
            #pragma unroll
            for (int kc = 0; kc < 4; ++kc) {
                float4 ga = *(const float4*)(g2 + kc * 32 + lg * 8);
                float4 gb = *(const float4*)(g2 + kc * 32 + lg * 8 + 4);
                float4 ba = *(const float4*)(be2 + kc * 32 + lg * 8);
                float4 bb = *(const float4*)(be2 + kc * 32 + lg * 8 + 4);
                uint u0 = pk2bf(xv[tf][kc][0] * rs * ga.x + ba.x, xv[tf][kc][1] * rs * ga.y + ba.y);
                uint u1 = pk2bf(xv[tf][kc][2] * rs * ga.z + ba.z, xv[tf][kc][3] * rs * ga.w + ba.w);
                uint u2 = pk2bf(xv[tf][kc][4] * rs * gb.x + bb.x, xv[tf][kc][5] * rs * gb.y + bb.y);
                uint u3 = pk2bf(xv[tf][kc][6] * rs * gb.z + bb.z, xv[tf][kc][7] * rs * gb.w + bb.w);
                uint4 u = {u0, u1, u2, u3};
                hfr[tf][kc] = __builtin_bit_cast(sv8, u);
            }
        }
    }

    // ---- 16 chunks of 32 hidden: MLP1(swapped) -> gelu -> transpose -> MLP2 partial
    f32x4 acc2[2][8] = {};
    #pragma unroll 2
    for (int hc = 0; hc < 16; ++hc) {
        int cb = hc & 1;
        f32x4 as[2][2] = {};   // [hf][tf]; lane: h = hc*32+hf*16+lg*4+r, token = tf*16+lr
        #pragma unroll
        for (int kc = 0; kc < 4; ++kc) {
            sv8 w0 = *(const sv8*)(w1T + (size_t)(hc * 32 + lr) * Cc + kc * 32 + lg * 8);
            sv8 w1f = *(const sv8*)(w1T + (size_t)(hc * 32 + 16 + lr) * Cc + kc * 32 + lg * 8);
            as[0][0] = mfma16(w0, hfr[0][kc], as[0][0]);
            as[0][1] = mfma16(w0, hfr[1][kc], as[0][1]);
            as[1][0] = mfma16(w1f, hfr[0][kc], as[1][0]);
            as[1][1] = mfma16(w1f, hfr[1][kc], as[1][1]);
        }
        #pragma unroll
        for (int hf = 0; hf < 2; ++hf) {
            float4 bs = *(const float4*)(b1 + hc * 32 + hf * 16 + lg * 4);
            #pragma unroll
            for (int tf = 0; tf < 2; ++tf) {
                uint2 pk;
                pk.x = pk2bf(fast_gelu(as[hf][tf][0] + bs.x), fast_gelu(as[hf][tf][1] + bs.y));
                pk.y = pk2bf(fast_gelu(as[hf][tf][2] + bs.z), fast_gelu(as[hf][tf][3] + bs.w));
                *(uint2*)&sc[wave][cb][tf * 16 + lr][hf * 16 + lg * 4] = pk;
            }
        }
        // wave-private LDS: same-wave ds ordering via lgkmcnt (compiler-inserted), no barrier
        sv8 a0 = *(const sv8*)&sc[wave][cb][lr][lg * 8];
        sv8 a1 = *(const sv8*)&sc[wave][cb][16 + lr][lg * 8];
        #pragma unroll
        for (int cf = 0; cf < 8; ++cf) {
            sv8 bv = *(const sv8*)(w2T + (size_t)(cf * 16 + lr) * 512 + hc * 32 + lg * 8);
            acc2[0][cf] = mfma16(a0, bv, acc2[0][cf]);
            acc2[1][cf] = mfma16(a1, bv, acc2[1][cf]);
        }
    }

    // ---- epilogue: bias + residual, direct stores (64B-coalesced across lr)
    #pragma unroll
    for (int cf = 0; cf < 8; ++cf) {
        float bs = b2[cf * 16 + lr];
        #pragma unroll
        for (int tf = 0; tf < 2; ++tf)
            #pragma unroll
            for (int r = 0; r < 4; ++r) {
                int row = t0 + tf * 16 + lg * 4 + r;
                size_t ad = (size_t)row * Cc + cf * 16 + lr;
                xdst[ad] = xsrc[ad] + acc2[tf][cf][r] + bs;
            }
    }
}

extern "C" void kernel_launch(void* const* d_in, const int* in_sizes, int n_in,
                              void* d_out, int out_size, void* d_ws, size_t ws_size,
                              hipStream_t stream) {
    const float* x_in   = (const float*)d_in[0];
    const float* g1     = (const float*)d_in[1];
    const float* be1    = (const float*)d_in[2];
    const float* Wqkv   = (const float*)d_in[3];
    const float* bqkv   = (const float*)d_in[4];
    const float* relb   = (const float*)d_in[5];
    const float* Wproj  = (const float*)d_in[6];
    const float* bproj  = (const float*)d_in[7];
    const float* g2     = (const float*)d_in[8];
    const float* be2    = (const float*)d_in[9];
    const float* W1     = (const float*)d_in[10];
    const float* b1     = (const float*)d_in[11];
    const float* W2     = (const float*)d_in[12];
    const float* b2     = (const float*)d_in[13];
    const int*   wid    = (const int*)d_in[14];

    size_t off = 0;
    float* x_ws = (float*)d_ws;                      off += (size_t)BN * Cc * 4;
    ushort* wt  = (ushort*)((char*)d_ws + off);      off += (size_t)786432 * 2;
    int* sidx   = (int*)((char*)d_ws + off);         off += (size_t)Nn * 4;
    int* lrank  = (int*)((char*)d_ws + off);         off += (size_t)Nn * 4;
    int* hist   = (int*)((char*)d_ws + off);         off += (size_t)NWw * NWw * 4;
    if (ws_size < off) return;

    rank_kernel<<<Nn / 64, 64, 0, stream>>>(wid, lrank, hist);
    prefix_kernel<<<NWw, 64, 0, stream>>>(hist);
    scatter_kernel<<<Nn / 64, 64, 0, stream>>>(wid, lrank, hist, sidx);
    wconv_kernel<<<786432 / 256, 256, 0, stream>>>(Wqkv, Wproj, W1, W2, wt);

    for (int l = 0; l < Ll; ++l) {
        const ushort* wqkvT  = wt + (size_t)l * 196608;
        const ushort* wprojT = wqkvT + 49152;
        const ushort* w1T    = wqkvT + 65536;
        const ushort* w2T    = wqkvT + 131072;
        const float* xsrc = (l == 0) ? x_in : x_ws;

        attn_fused_kernel<<<BN / 64, 256, 0, stream>>>(
            xsrc, x_ws, wqkvT, bqkv + l * 384, relb + l * Hh,
            wprojT, bproj + l * Cc, g1 + l * Cc, be1 + l * Cc, sidx);

        float* xdst = (l == Ll - 1) ? (float*)d_out : x_ws;
        mlp_fused_kernel<<<BN / 128, 256, 0, stream>>>(
            x_ws, xdst, w1T, b1 + l * 512, w2T, b2 + l * Cc,
            g2 + l * Cc, be2 + l * Cc);
    }
}

// Round 8
// 456.269 us; speedup vs baseline: 1.3682x; 1.3682x over previous
//
#include <hip/hip_runtime.h>
#include <hip/hip_bf16.h>
#include <math.h>

#define Nn 20480
#define Cc 128
#define Hh 8
#define Ll 4
#define NWw 320
#define BN 81920   // B*N

typedef short sv8 __attribute__((ext_vector_type(8)));
typedef __bf16 bfv8 __attribute__((ext_vector_type(8)));
typedef float f32x4 __attribute__((ext_vector_type(4)));

__device__ __forceinline__ f32x4 mfma16(sv8 a, sv8 b, f32x4 c) {
    return __builtin_amdgcn_mfma_f32_16x16x32_bf16(
        __builtin_bit_cast(bfv8, a), __builtin_bit_cast(bfv8, b), c, 0, 0, 0);
}
__device__ __forceinline__ ushort f2bf(float f) {
    uint u = __float_as_uint(f);
    u += 0x7fffu + ((u >> 16) & 1u);
    return (ushort)(u >> 16);
}
// packed f32 pair -> 2 bf16 in one VALU op (RNE, matches f2bf)
__device__ __forceinline__ uint pk2bf(float lo, float hi) {
    uint r;
    asm("v_cvt_pk_bf16_f32 %0, %1, %2" : "=v"(r) : "v"(lo), "v"(hi));
    return r;
}
__device__ __forceinline__ float fast_gelu(float x) {
    float z = 0.7978845608f * (x + 0.044715f * x * x * x);
    return x * __builtin_amdgcn_rcpf(1.0f + __expf(-2.0f * z));
}

// ---------- stable counting sort of window_ids ----------
__global__ __launch_bounds__(64) void rank_kernel(const int* __restrict__ wid,
        int* __restrict__ lrank, int* __restrict__ hist) {
    __shared__ int keys[64];
    int c = blockIdx.x, lane = threadIdx.x;
    for (int j = lane; j < NWw; j += 64) hist[c * NWw + j] = 0;
    int i = c * 64 + lane;
    int w = wid[i];
    keys[lane] = w;
    __syncthreads();
    int rank = 0, total = 0;
    for (int j = 0; j < 64; ++j) {
        int kj = keys[j];
        total += (kj == w);
        rank += (j < lane && kj == w) ? 1 : 0;
    }
    lrank[i] = rank;
    if (rank == 0) hist[c * NWw + w] = total;
}
__global__ __launch_bounds__(64) void prefix_kernel(int* __restrict__ hist) {
    int w = blockIdx.x, lane = threadIdx.x;
    int running = 0;
    for (int it = 0; it < NWw / 64; ++it) {
        int c = it * 64 + lane;
        int v = hist[c * NWw + w];
        int orig = v;
        #pragma unroll
        for (int d = 1; d < 64; d <<= 1) {
            int tt = __shfl_up(v, d, 64);
            if (lane >= d) v += tt;
        }
        hist[c * NWw + w] = running + v - orig;
        running += __shfl(v, 63, 64);
    }
}
__global__ __launch_bounds__(64) void scatter_kernel(const int* __restrict__ wid,
        const int* __restrict__ lrank, const int* __restrict__ hist,
        int* __restrict__ sidx) {
    int c = blockIdx.x, lane = threadIdx.x;
    int i = c * 64 + lane;
    int w = wid[i];
    sidx[w * 64 + hist[c * NWw + w] + lrank[i]] = i;
}

// ---------- weight convert + transpose to bf16 [N][K] ----------
__global__ __launch_bounds__(256) void wconv_kernel(
    const float* __restrict__ Wqkv, const float* __restrict__ Wproj,
    const float* __restrict__ W1, const float* __restrict__ W2,
    ushort* __restrict__ wt) {
    int id = blockIdx.x * 256 + threadIdx.x;      // < 786432
    int l = id / 196608;
    int r = id % 196608;
    const float* src; int dst;
    if (r < 49152) { int n = r % 384, k = r / 384;
        src = Wqkv + l * 49152 + k * 384 + n; dst = l * 196608 + n * 128 + k; }
    else if (r < 65536) { int rr = r - 49152; int n = rr % 128, k = rr / 128;
        src = Wproj + l * 16384 + k * 128 + n; dst = l * 196608 + 49152 + n * 128 + k; }
    else if (r < 131072) { int rr = r - 65536; int n = rr % 512, k = rr / 512;
        src = W1 + l * 65536 + k * 512 + n; dst = l * 196608 + 65536 + n * 128 + k; }
    else { int rr = r - 131072; int n = rr % 128, k = rr / 128;
        src = W2 + l * 65536 + k * 128 + n; dst = l * 196608 + 131072 + n * 512 + k; }
    wt[dst] = f2bf(*src);
}

// ---------- fused attention block (unchanged) ----------
__global__ __launch_bounds__(256, 2) void attn_fused_kernel(
    const float* __restrict__ xsrc, float* __restrict__ xdst,
    const ushort* __restrict__ wqkvT, const float* __restrict__ bqkv,
    const float* __restrict__ relb, const ushort* __restrict__ wprojT,
    const float* __restrict__ bproj, const float* __restrict__ g1,
    const float* __restrict__ be1, const int* __restrict__ sidx) {
    __shared__ __align__(16) ushort hl_[64][128];
    __shared__ __align__(16) ushort qkn[64][256];
    __shared__ __align__(16) ushort vT[128][76];
    __shared__ __align__(16) ushort pt[4][16][76];
    __shared__ int ridx[64];

    int t = threadIdx.x;
    int wave = t >> 6, lane = t & 63;
    int lr = lane & 15, lg = lane >> 4;
    int wb = blockIdx.x;
    int bN = (wb / NWw) * Nn;
    int p0 = (wb % NWw) * 64;

    if (t < 64) ridx[t] = sidx[p0 + t];
    __syncthreads();

    // ---- phase 1: gather + LN1 -> hl_ (bf16, swizzled)
    {
        int hl2 = lane & 31, hb = lane >> 5;
        float4 gg = *(const float4*)(g1 + hl2 * 4);
        float4 bb = *(const float4*)(be1 + hl2 * 4);
        #pragma unroll
        for (int it = 0; it < 8; ++it) {
            int row = it * 8 + wave * 2 + hb;
            int gi = bN + ridx[row];
            float4 v = *(const float4*)(xsrc + (size_t)gi * Cc + hl2 * 4);
            float s = v.x + v.y + v.z + v.w;
            s += __shfl_xor(s, 1, 64);  s += __shfl_xor(s, 2, 64);
            s += __shfl_xor(s, 4, 64);  s += __shfl_xor(s, 8, 64);
            s += __shfl_xor(s, 16, 64);
            float mu = s * 0.0078125f;
            float d0 = v.x - mu, d1 = v.y - mu, d2 = v.z - mu, d3 = v.w - mu;
            float q = d0 * d0 + d1 * d1 + d2 * d2 + d3 * d3;
            q += __shfl_xor(q, 1, 64);  q += __shfl_xor(q, 2, 64);
            q += __shfl_xor(q, 4, 64);  q += __shfl_xor(q, 8, 64);
            q += __shfl_xor(q, 16, 64);
            float rs = rsqrtf(q * 0.0078125f + 1e-5f);
            uint2 pk;
            pk.x = pk2bf(d0 * rs * gg.x + bb.x, d1 * rs * gg.y + bb.y);
            pk.y = pk2bf(d2 * rs * gg.z + bb.z, d3 * rs * gg.w + bb.w);
            *(uint2*)&hl_[row][(hl2 * 4) ^ ((row & 7) << 3)] = pk;
        }
    }
    __syncthreads();

    // ---- phase 2: QKV GEMM; wave computes its own 2 heads' q,k,v (96 cols)
    {
        f32x4 acc[4][6] = {};
        #pragma unroll
        for (int ks = 0; ks < 4; ++ks) {
            int k0 = ks * 32 + lg * 8;
            sv8 a[4], b[6];
            #pragma unroll
            for (int rf = 0; rf < 4; ++rf) {
                int row = rf * 16 + lr;
                a[rf] = *(const sv8*)&hl_[row][k0 ^ ((row & 7) << 3)];
            }
            #pragma unroll
            for (int nf = 0; nf < 6; ++nf) {
                int gcol = (nf < 2 ? 32 * wave + nf * 16
                          : nf < 4 ? 128 + 32 * wave + (nf - 2) * 16
                                   : 256 + 32 * wave + (nf - 4) * 16) + lr;
                b[nf] = *(const sv8*)(wqkvT + (size_t)gcol * 128 + k0);
            }
            #pragma unroll
            for (int rf = 0; rf < 4; ++rf)
                #pragma unroll
                for (int nf = 0; nf < 6; ++nf)
                    acc[rf][nf] = mfma16(a[rf], b[nf], acc[rf][nf]);
        }
        #pragma unroll
        for (int nf = 0; nf < 6; ++nf) {
            int gcol = (nf < 2 ? 32 * wave + nf * 16
                      : nf < 4 ? 128 + 32 * wave + (nf - 2) * 16
                               : 256 + 32 * wave + (nf - 4) * 16) + lr;
            float bs = bqkv[gcol];
            if (nf < 4) {
                #pragma unroll
                for (int rf = 0; rf < 4; ++rf)
                    #pragma unroll
                    for (int r = 0; r < 4; ++r) {
                        int row = rf * 16 + lg * 4 + r;
                        qkn[row][gcol ^ ((row & 7) << 3)] = f2bf(acc[rf][nf][r] + bs);
                    }
            } else {
                int dcol = gcol - 256;
                #pragma unroll
                for (int rf = 0; rf < 4; ++rf) {
                    uint2 pk;
                    pk.x = pk2bf(acc[rf][nf][0] + bs, acc[rf][nf][1] + bs);
                    pk.y = pk2bf(acc[rf][nf][2] + bs, acc[rf][nf][3] + bs);
                    *(uint2*)&vT[dcol][rf * 16 + lg * 4] = pk;
                }
            }
        }
    }
    __syncthreads();

    // ---- phase 3: attention via swapped QK^T (S^T = K Q^T), 2 heads per wave
    f32x4 zz = {0.f, 0.f, 0.f, 0.f};
    #pragma unroll
    for (int hi = 0; hi < 2; ++hi) {
        int hh = wave * 2 + hi;
        float rb = relb[hh];
        sv8 bv[2];
        #pragma unroll
        for (int ks = 0; ks < 2; ++ks)
            bv[ks] = *(const sv8*)&vT[hh * 16 + lr][ks * 32 + lg * 8];
        sv8 aq[4], bk[4];
        sv8 z = {0, 0, 0, 0, 0, 0, 0, 0};
        bool lo = (lg < 2);
        #pragma unroll
        for (int f = 0; f < 4; ++f) {
            aq[f] = z; bk[f] = z;
            if (lo) {
                int row = f * 16 + lr;
                aq[f] = *(const sv8*)&qkn[row][(hh * 16 + lg * 8) ^ ((row & 7) << 3)];
                bk[f] = *(const sv8*)&qkn[row][(128 + hh * 16 + lg * 8) ^ ((row & 7) << 3)];
            }
        }
        f32x4 s[4][4];
        #pragma unroll
        for (int kt = 0; kt < 4; ++kt)
            #pragma unroll
            for (int qt = 0; qt < 4; ++qt)
                s[kt][qt] = mfma16(bk[kt], aq[qt], zz);

        f32x4 o[4];
        #pragma unroll
        for (int qt = 0; qt < 4; ++qt) {
            float v[16];
            #pragma unroll
            for (int kt = 0; kt < 4; ++kt)
                #pragma unroll
                for (int r = 0; r < 4; ++r)
                    v[kt * 4 + r] = s[kt][qt][r] * 0.25f + rb;
            float m0 = fmaxf(fmaxf(fmaxf(v[0], v[1]), fmaxf(v[2], v[3])),
                             fmaxf(fmaxf(v[4], v[5]), fmaxf(v[6], v[7])));
            float m1 = fmaxf(fmaxf(fmaxf(v[8], v[9]), fmaxf(v[10], v[11])),
                             fmaxf(fmaxf(v[12], v[13]), fmaxf(v[14], v[15])));
            float mx = fmaxf(m0, m1);
            mx = fmaxf(mx, __shfl_xor(mx, 16, 64));
            mx = fmaxf(mx, __shfl_xor(mx, 32, 64));
            float sum = 0.f;
            #pragma unroll
            for (int i = 0; i < 16; ++i) {
                v[i] = __expf(v[i] - mx);
                sum += v[i];
            }
            sum += __shfl_xor(sum, 16, 64);
            sum += __shfl_xor(sum, 32, 64);
            float inv = __builtin_amdgcn_rcpf(sum);
            #pragma unroll
            for (int kt = 0; kt < 4; ++kt) {
                uint2 pk;
                pk.x = pk2bf(v[kt * 4 + 0] * inv, v[kt * 4 + 1] * inv);
                pk.y = pk2bf(v[kt * 4 + 2] * inv, v[kt * 4 + 3] * inv);
                *(uint2*)&pt[wave][lr][kt * 16 + lg * 4] = pk;
            }
            sv8 ap0 = *(const sv8*)&pt[wave][lr][lg * 8];
            sv8 ap1 = *(const sv8*)&pt[wave][lr][32 + lg * 8];
            o[qt] = mfma16(ap0, bv[0], zz);
            o[qt] = mfma16(ap1, bv[1], o[qt]);
        }
        #pragma unroll
        for (int qt = 0; qt < 4; ++qt)
            #pragma unroll
            for (int r = 0; r < 4; ++r) {
                int row = qt * 16 + lg * 4 + r;
                hl_[row][(hh * 16 + lr) ^ ((row & 7) << 3)] = f2bf(o[qt][r]);
            }
    }
    __syncthreads();

    // ---- phase 4: proj + bias + residual, scatter to original rows
    {
        f32x4 acc[4][2] = {};
        #pragma unroll
        for (int ks = 0; ks < 4; ++ks) {
            int k0 = ks * 32 + lg * 8;
            sv8 a[4], b[2];
            #pragma unroll
            for (int rf = 0; rf < 4; ++rf) {
                int row = rf * 16 + lr;
                a[rf] = *(const sv8*)&hl_[row][k0 ^ ((row & 7) << 3)];
            }
            #pragma unroll
            for (int nf = 0; nf < 2; ++nf)
                b[nf] = *(const sv8*)(wprojT + (size_t)(wave * 32 + nf * 16 + lr) * 128 + k0);
            #pragma unroll
            for (int rf = 0; rf < 4; ++rf)
                #pragma unroll
                for (int nf = 0; nf < 2; ++nf)
                    acc[rf][nf] = mfma16(a[rf], b[nf], acc[rf][nf]);
        }
        #pragma unroll
        for (int nf = 0; nf < 2; ++nf) {
            int col = wave * 32 + nf * 16 + lr;
            float bs = bproj[col];
            #pragma unroll
            for (int rf = 0; rf < 4; ++rf)
                #pragma unroll
                for (int r = 0; r < 4; ++r) {
                    int row = rf * 16 + lg * 4 + r;
                    int gi = bN + ridx[row];
                    size_t ad = (size_t)gi * Cc + col;
                    xdst[ad] = xsrc[ad] + acc[rf][nf][r] + bs;
                }
        }
    }
}

// ---------- fused MLP block: LN2 -> MLP1+GELU -> MLP2+residual (R2 structure) ----------
__global__ __launch_bounds__(256, 2) void mlp_fused_kernel(
    const float* __restrict__ xsrc, float* __restrict__ xdst,
    const ushort* __restrict__ w1T, const float* __restrict__ b1,
    const ushort* __restrict__ w2T, const float* __restrict__ b2,
    const float* __restrict__ g2, const float* __restrict__ be2) {
    __shared__ __align__(16) ushort hl_[64][128];
    __shared__ __align__(16) ushort hid[64][512];
    int t = threadIdx.x, wave = t >> 6, lane = t & 63;
    int lr = lane & 15, lg = lane >> 4;
    int r0 = blockIdx.x * 64;

    // phase 1: LN2
    {
        int hl2 = lane & 31, hb = lane >> 5;
        float4 gg = *(const float4*)(g2 + hl2 * 4);
        float4 bb = *(const float4*)(be2 + hl2 * 4);
        #pragma unroll
        for (int it = 0; it < 8; ++it) {
            int row = it * 8 + wave * 2 + hb;
            float4 v = *(const float4*)(xsrc + (size_t)(r0 + row) * Cc + hl2 * 4);
            float s = v.x + v.y + v.z + v.w;
            s += __shfl_xor(s, 1, 64);  s += __shfl_xor(s, 2, 64);
            s += __shfl_xor(s, 4, 64);  s += __shfl_xor(s, 8, 64);
            s += __shfl_xor(s, 16, 64);
            float mu = s * 0.0078125f;
            float d0 = v.x - mu, d1 = v.y - mu, d2 = v.z - mu, d3 = v.w - mu;
            float q = d0 * d0 + d1 * d1 + d2 * d2 + d3 * d3;
            q += __shfl_xor(q, 1, 64);  q += __shfl_xor(q, 2, 64);
            q += __shfl_xor(q, 4, 64);  q += __shfl_xor(q, 8, 64);
            q += __shfl_xor(q, 16, 64);
            float rs = rsqrtf(q * 0.0078125f + 1e-5f);
            uint2 pk;
            pk.x = pk2bf(d0 * rs * gg.x + bb.x, d1 * rs * gg.y + bb.y);
            pk.y = pk2bf(d2 * rs * gg.z + bb.z, d3 * rs * gg.w + bb.w);
            *(uint2*)&hl_[row][(hl2 * 4) ^ ((row & 7) << 3)] = pk;
        }
    }
    __syncthreads();

    // phase 2: MLP1 + gelu -> hid (wave -> 128 cols)
    {
        f32x4 acc[4][8] = {};
        #pragma unroll
        for (int ks = 0; ks < 4; ++ks) {
            int k0 = ks * 32 + lg * 8;
            sv8 a[4], b[8];
            #pragma unroll
            for (int rf = 0; rf < 4; ++rf) {
                int row = rf * 16 + lr;
                a[rf] = *(const sv8*)&hl_[row][k0 ^ ((row & 7) << 3)];
            }
            #pragma unroll
            for (int nf = 0; nf < 8; ++nf)
                b[nf] = *(const sv8*)(w1T + (size_t)(wave * 128 + nf * 16 + lr) * 128 + k0);
            #pragma unroll
            for (int rf = 0; rf < 4; ++rf)
                #pragma unroll
                for (int nf = 0; nf < 8; ++nf)
                    acc[rf][nf] = mfma16(a[rf], b[nf], acc[rf][nf]);
        }
        #pragma unroll
        for (int nf = 0; nf < 8; ++nf) {
            int col = wave * 128 + nf * 16 + lr;
            float bs = b1[col];
            #pragma unroll
            for (int rf = 0; rf < 4; ++rf)
                #pragma unroll
                for (int r = 0; r < 4; ++r) {
                    int row = rf * 16 + lg * 4 + r;
                    hid[row][col ^ ((row & 7) << 3)] = f2bf(fast_gelu(acc[rf][nf][r] + bs));
                }
        }
    }
    __syncthreads();

    // phase 3: MLP2 + bias + residual (wave -> 32 cols, K=512), direct epilogue
    {
        f32x4 acc2[4][2] = {};
        #pragma unroll
        for (int ks = 0; ks < 16; ++ks) {
            int k0 = ks * 32 + lg * 8;
            sv8 a[4], b[2];
            #pragma unroll
            for (int rf = 0; rf < 4; ++rf) {
                int row = rf * 16 + lr;
                a[rf] = *(const sv8*)&hid[row][k0 ^ ((row & 7) << 3)];
            }
            #pragma unroll
            for (int nf = 0; nf < 2; ++nf)
                b[nf] = *(const sv8*)(w2T + (size_t)(wave * 32 + nf * 16 + lr) * 512 + k0);
            #pragma unroll
            for (int rf = 0; rf < 4; ++rf)
                #pragma unroll
                for (int nf = 0; nf < 2; ++nf)
                    acc2[rf][nf] = mfma16(a[rf], b[nf], acc2[rf][nf]);
        }
        #pragma unroll
        for (int nf = 0; nf < 2; ++nf) {
            int col = wave * 32 + nf * 16 + lr;
            float bs = b2[col];
            #pragma unroll
            for (int rf = 0; rf < 4; ++rf)
                #pragma unroll
                for (int r = 0; r < 4; ++r) {
                    int row = rf * 16 + lg * 4 + r;
                    size_t ad = (size_t)(r0 + row) * Cc + col;
                    xdst[ad] = xsrc[ad] + acc2[rf][nf][r] + bs;
                }
        }
    }
}

extern "C" void kernel_launch(void* const* d_in, const int* in_sizes, int n_in,
                              void* d_out, int out_size, void* d_ws, size_t ws_size,
                              hipStream_t stream) {
    const float* x_in   = (const float*)d_in[0];
    const float* g1     = (const float*)d_in[1];
    const float* be1    = (const float*)d_in[2];
    const float* Wqkv   = (const float*)d_in[3];
    const float* bqkv   = (const float*)d_in[4];
    const float* relb   = (const float*)d_in[5];
    const float* Wproj  = (const float*)d_in[6];
    const float* bproj  = (const float*)d_in[7];
    const float* g2     = (const float*)d_in[8];
    const float* be2    = (const float*)d_in[9];
    const float* W1     = (const float*)d_in[10];
    const float* b1     = (const float*)d_in[11];
    const float* W2     = (const float*)d_in[12];
    const float* b2     = (const float*)d_in[13];
    const int*   wid    = (const int*)d_in[14];

    size_t off = 0;
    float* x_ws = (float*)d_ws;                      off += (size_t)BN * Cc * 4;
    ushort* wt  = (ushort*)((char*)d_ws + off);      off += (size_t)786432 * 2;
    int* sidx   = (int*)((char*)d_ws + off);         off += (size_t)Nn * 4;
    int* lrank  = (int*)((char*)d_ws + off);         off += (size_t)Nn * 4;
    int* hist   = (int*)((char*)d_ws + off);         off += (size_t)NWw * NWw * 4;
    if (ws_size < off) return;

    rank_kernel<<<Nn / 64, 64, 0, stream>>>(wid, lrank, hist);
    prefix_kernel<<<NWw, 64, 0, stream>>>(hist);
    scatter_kernel<<<Nn / 64, 64, 0, stream>>>(wid, lrank, hist, sidx);
    wconv_kernel<<<786432 / 256, 256, 0, stream>>>(Wqkv, Wproj, W1, W2, wt);

    for (int l = 0; l < Ll; ++l) {
        const ushort* wqkvT  = wt + (size_t)l * 196608;
        const ushort* wprojT = wqkvT + 49152;
        const ushort* w1T    = wqkvT + 65536;
        const ushort* w2T    = wqkvT + 131072;
        const float* xsrc = (l == 0) ? x_in : x_ws;

        attn_fused_kernel<<<BN / 64, 256, 0, stream>>>(
            xsrc, x_ws, wqkvT, bqkv + l * 384, relb + l * Hh,
            wprojT, bproj + l * Cc, g1 + l * Cc, be1 + l * Cc, sidx);

        float* xdst = (l == Ll - 1) ? (float*)d_out : x_ws;
        mlp_fused_kernel<<<BN / 64, 256, 0, stream>>>(
            x_ws, xdst, w1T, b1 + l * 512, w2T, b2 + l * Cc,
            g2 + l * Cc, be2 + l * Cc);
    }
}